// Round 1
// 144.104 us; speedup vs baseline: 1.0161x; 1.0161x over previous
//
#include <hip/hip_runtime.h>

#define N_ 4
#define C_ 256
#define H_ 128
#define W_ 128
#define HW_ (H_*W_)
#define BINS 256      // 16x16 pooled positions
#define OC 9
#define EPS_ 1e-5f

typedef float nfloat4 __attribute__((ext_vector_type(4)));

// Kernel 1: 8x8 average pool, atomic-free. Block per (n,c), 256 threads,
// fully-coalesced float4 reads. shfl_xor collapses each wave's partials;
// output transposed: xpT[c][n*256+bin] so stage 2 reads coalesced.
__global__ __launch_bounds__(256) void pool_kernel(const float* __restrict__ x,
                                                   float* __restrict__ xpT) {
    int b = blockIdx.x;          // n*C + c
    int n = b >> 8, c = b & 255;
    const float4* xv = (const float4*)(x + (size_t)b * HW_);
    __shared__ float part[4 * 256];
    int t = threadIdx.x;
    int w = t >> 6, l = t & 63;
    int j = (l & 31) >> 1;       // col bin 0..15
    bool writer = (l < 32) && ((l & 1) == 0);
    #pragma unroll
    for (int k = 0; k < 16; ++k) {
        float4 v = xv[k * 256 + t];   // coalesced: flat pixel = k*1024 + 4t
        float s = v.x + v.y + v.z + v.w;
        s += __shfl_xor(s, 1);        // pair lanes -> 8 cols of one row
        s += __shfl_xor(s, 32);       // combine the wave's two rows
        if (writer) part[w * 256 + k * 16 + j] = s;
    }
    __syncthreads();
    float r = part[t] + part[256 + t] + part[512 + t] + part[768 + t];
    xpT[((size_t)c << 10) + (n << 8) + t] = r * (1.f / 64.f);
}

// Kernel 2: fused 1x1 conv + BatchNorm, latency-optimized.
// Block per output channel o (9 blocks), 1024 threads.
// c-sum split 4 ways: thread (q, ch) accumulates 64 channels for sample
// quad 4q..4q+3 via float4 loads -> 4 exposed latency batches (was 16)
// and 4x fewer load instructions. LDS reduce across the 4 c-chunks,
// then standard wave/LDS reduction for BN stats.
__global__ __launch_bounds__(1024) void convbn_kernel(const float* __restrict__ xpT,
                                                      const float* __restrict__ wconv,
                                                      const float* __restrict__ gamma,
                                                      const float* __restrict__ beta,
                                                      float* __restrict__ w9) {
    int o = blockIdx.x;
    int t = threadIdx.x;
    int q = t & 255;          // sample quad: samples 4q..4q+3
    int ch = t >> 8;          // c-chunk 0..3 (64 channels each)
    const float4* xp4 = (const float4*)xpT;   // [c][256 quads]
    const float* wrow = wconv + (o << 8);
    float ax = 0.f, ay = 0.f, az = 0.f, aw = 0.f;
    int c0 = ch << 6;
    #pragma unroll 16
    for (int c = c0; c < c0 + 64; ++c) {
        float wv = wrow[c];
        float4 v = xp4[(c << 8) + q];
        ax += wv * v.x; ay += wv * v.y; az += wv * v.z; aw += wv * v.w;
    }
    __shared__ float red[3][256][4];
    if (ch) {
        red[ch-1][q][0] = ax; red[ch-1][q][1] = ay;
        red[ch-1][q][2] = az; red[ch-1][q][3] = aw;
    }
    __syncthreads();
    __shared__ float ls[32];
    __shared__ float sc[2];
    if (ch == 0) {
        ax += red[0][q][0] + red[1][q][0] + red[2][q][0];
        ay += red[0][q][1] + red[1][q][1] + red[2][q][1];
        az += red[0][q][2] + red[1][q][2] + red[2][q][2];
        aw += red[0][q][3] + red[1][q][3] + red[2][q][3];
        float sum = ax + ay + az + aw;
        float sq  = ax*ax + ay*ay + az*az + aw*aw;
        #pragma unroll
        for (int off = 32; off > 0; off >>= 1) {
            sum += __shfl_down(sum, off);
            sq  += __shfl_down(sq,  off);
        }
        if ((q & 63) == 0) { ls[q >> 6] = sum; ls[16 + (q >> 6)] = sq; }
    }
    __syncthreads();
    if (t == 0) {
        float S = ls[0] + ls[1] + ls[2] + ls[3];
        float Q = ls[16] + ls[17] + ls[18] + ls[19];
        float mu = S * (1.f / 1024.f);
        float var = Q * (1.f / 1024.f) - mu * mu;
        float scale = gamma[o] * rsqrtf(var + EPS_);
        sc[0] = scale;
        sc[1] = beta[o] - mu * scale;
    }
    __syncthreads();
    if (ch == 0) {
        float scale = sc[0], shift = sc[1];
        int s0 = q << 2;
        w9[(s0 + 0) * 9 + o] = ax * scale + shift;
        w9[(s0 + 1) * 9 + o] = ay * scale + shift;
        w9[(s0 + 2) * 9 + o] = az * scale + shift;
        w9[(s0 + 3) * 9 + o] = aw * scale + shift;
    }
}

// Kernel 3: depthwise 3x3 conv, per-(n,ch) dynamic 9-tap kernel, zero pad 1.
// Block per (n,ch,row-tile of 32): halo overhead 34/32 = +6.25%.
// LDS tile 34 rows x 132 (16B-aligned row stride; col x at index x+1; halo
// cols zeroed). Each thread computes a 4-row x 4-col micro-tile.
// out is written with NONTEMPORAL stores so the 67 MB write stream does not
// write-allocate into L3 and evict the L3-resident x we are re-reading.
__global__ __launch_bounds__(256) void dwconv_kernel(const float* __restrict__ x,
                                                     const float* __restrict__ w9,
                                                     float* __restrict__ out) {
    int b = blockIdx.x;
    int plane = b >> 2;          // n*C + ch
    int rt = b & 3;
    int r0 = rt * 32;
    const float* xin = x + (size_t)plane * HW_;
    float* po = out + (size_t)plane * HW_;
    const float* wp = w9 + plane * 9;    // block-uniform -> scalar loads
    float w[9];
    #pragma unroll
    for (int i = 0; i < 9; ++i) w[i] = wp[i];

    __shared__ __align__(16) float lds[34 * 132];
    int t = threadIdx.x;
    if (t < 34) {                 // zero halo columns (col -1 and col 128)
        lds[t * 132] = 0.f;
        lds[t * 132 + 129] = 0.f;
    }
    // stage 34 rows x 128 cols = 1088 float4 loads, coalesced
    #pragma unroll
    for (int i = 0; i < 5; ++i) {
        int vi = i * 256 + t;
        if (vi < 1088) {
            int lr = vi >> 5;            // lds row 0..33
            int c4 = (vi & 31) << 2;     // col 0,4,...,124
            int gr = r0 - 1 + lr;        // global row
            float4 val = make_float4(0.f, 0.f, 0.f, 0.f);
            if (gr >= 0 && gr < H_) val = *(const float4*)&xin[gr * W_ + c4];
            float* d = &lds[lr * 132 + c4 + 1];
            d[0] = val.x; d[1] = val.y; d[2] = val.z; d[3] = val.w;
        }
    }
    __syncthreads();

    int mr = t >> 5;              // 0..7  -> out rows mr*4 .. mr*4+3
    int mc = t & 31;              // 0..31 -> out cols mc*4 .. mc*4+3
    int olr = mr * 4;
    int oc0 = mc * 4;
    // rowv[j][i] = input col (oc0 + i - 1) of lds row (olr + j), j=0..5
    float rowv[6][6];
    #pragma unroll
    for (int j = 0; j < 6; ++j) {
        const float* rp = &lds[(olr + j) * 132 + oc0];
        float4 a = *(const float4*)rp;    // 16B-aligned ds_read_b128
        rowv[j][0] = a.x; rowv[j][1] = a.y; rowv[j][2] = a.z; rowv[j][3] = a.w;
        rowv[j][4] = rp[4]; rowv[j][5] = rp[5];
    }
    #pragma unroll
    for (int rr = 0; rr < 4; ++rr) {
        float res[4];
        #pragma unroll
        for (int cc = 0; cc < 4; ++cc) {
            float s = 0.f;
            #pragma unroll
            for (int dy = 0; dy < 3; ++dy)
                #pragma unroll
                for (int dx = 0; dx < 3; ++dx)
                    s += w[dy * 3 + dx] * rowv[rr + dy][cc + dx];
            res[cc] = s;
        }
        nfloat4 rv = { res[0], res[1], res[2], res[3] };
        __builtin_nontemporal_store(rv,
            (nfloat4*)&po[(r0 + olr + rr) * W_ + oc0]);
    }
}

extern "C" void kernel_launch(void* const* d_in, const int* in_sizes, int n_in,
                              void* d_out, int out_size, void* d_ws, size_t ws_size,
                              hipStream_t stream) {
    const float* x     = (const float*)d_in[0];
    const float* wconv = (const float*)d_in[1];
    const float* gamma = (const float*)d_in[2];
    const float* beta  = (const float*)d_in[3];
    float* out = (float*)d_out;

    float* xpT = (float*)d_ws;                  // C * N*BINS = 262144 floats
    float* w9  = xpT + C_ * N_ * BINS;          // N*BINS*OC  = 9216 floats

    pool_kernel  <<<N_ * C_,     256, 0, stream>>>(x, xpT);
    convbn_kernel<<<OC,         1024, 0, stream>>>(xpT, wconv, gamma, beta, w9);
    dwconv_kernel<<<N_ * C_ * 4, 256, 0, stream>>>(x, w9, out);
}